// Round 7
// baseline (178.948 us; speedup 1.0000x reference)
//
#include <hip/hip_runtime.h>
#include <stdint.h>

// Problem constants (from reference setup_inputs)
#define BNUM  8192
#define LROWS 32
#define MLAB  32
#define CCLS  96
#define WPB   4              // waves per block
#define SPW   2              // samples per wave (one per 32-lane half)
#define SPB   (WPB*SPW)      // 8 samples per block
#define NBLK  (BNUM/SPB)     // 1024 blocks
#define CEF   (LROWS*MLAB)   // 1024 floats of ce-table per sample

typedef float f32x4 __attribute__((ext_vector_type(4)));

// Design (round 7): break the lockstep phase serialization.
//  Model (fits r0..r6): grid is exactly resident (4 blocks/CU), so every wave
//  streams together (~16 us burst at near-peak BW) then computes together
//  (~36-40 us with memory idle). Total = burst + compute, serialized.
//  Split into two dispatches so each phase runs at its own roofline:
//   K1: stream x -> lse/pred -> sign-encoded ce table -> GLOBAL scratch
//       (row-major, coalesced 2x128B per store instr). Pure streaming.
//   K2: stage ce slice global->LDS (coalesced, L3-hot), then r6's Phase B
//       VERBATIM (same LDS layout/banks, same DPP wave_shr:1 chain, same
//       predication -> bit-identical results).
__device__ __forceinline__ int dpp_wshr1_i32(int v) {
    // dpp_ctrl 0x138 = wave_shr:1; lanes 0/32 bound_ctrl zeros are overridden
    // by the analytic column-0 injection (HW-verified exact, round 2).
    return __builtin_amdgcn_update_dpp(0, v, 0x138, 0xF, 0xF, true);
}
__device__ __forceinline__ float dpp_wshr1_f32(float v) {
    return __int_as_float(
        __builtin_amdgcn_update_dpp(0, __float_as_int(v), 0x138, 0xF, 0xF, true));
}

// ---------------- K1: streaming phase (argmax + lse + ce table) ------------
__global__ __launch_bounds__(256, 3) void editloss_k1(
    const float* __restrict__ x, const int* __restrict__ y,
    float* __restrict__ ceG)
{
    __shared__ float2 lpS[SPB][LROWS];   // 2 KB: {lse, (float)pred}

    const int w    = threadIdx.x >> 6;
    const int lane = threadIdx.x & 63;
    const int g    = lane >> 5;          // which sample of the wave
    const int u    = lane & 31;          // slot within 32-lane half
    const int s    = w * SPW + g;        // sample slot in block [0,8)
    const int sb   = blockIdx.x * SPB + s;

    const float* xs    = x + (size_t)sb * (LROWS * CCLS);
    const int    lab_u = y[sb * MLAB + u];

    // Issue ALL global loads back-to-back (r6 structure, HW-verified).
    const f32x4* rowv = (const f32x4*)(xs + (size_t)u * CCLS);
    f32x4 va[24];
#pragma unroll
    for (int t = 0; t < 24; ++t) va[t] = rowv[t];

    const float* gcol = xs + lab_u;       // x[:, lab_u], row stride CCLS
    float xg[LROWS];
#pragma unroll
    for (int r = 0; r < LROWS; ++r) xg[r] = gcol[r * CCLS];

    asm volatile("" :
        "+v"(va[0]),  "+v"(va[1]),  "+v"(va[2]),  "+v"(va[3]),
        "+v"(va[4]),  "+v"(va[5]),  "+v"(va[6]),  "+v"(va[7]),
        "+v"(va[8]),  "+v"(va[9]),  "+v"(va[10]), "+v"(va[11]),
        "+v"(va[12]), "+v"(va[13]), "+v"(va[14]), "+v"(va[15]),
        "+v"(va[16]), "+v"(va[17]), "+v"(va[18]), "+v"(va[19]),
        "+v"(va[20]), "+v"(va[21]), "+v"(va[22]), "+v"(va[23]));
    asm volatile("" :
        "+v"(xg[0]),  "+v"(xg[1]),  "+v"(xg[2]),  "+v"(xg[3]),
        "+v"(xg[4]),  "+v"(xg[5]),  "+v"(xg[6]),  "+v"(xg[7]),
        "+v"(xg[8]),  "+v"(xg[9]),  "+v"(xg[10]), "+v"(xg[11]),
        "+v"(xg[12]), "+v"(xg[13]), "+v"(xg[14]), "+v"(xg[15]),
        "+v"(xg[16]), "+v"(xg[17]), "+v"(xg[18]), "+v"(xg[19]),
        "+v"(xg[20]), "+v"(xg[21]), "+v"(xg[22]), "+v"(xg[23]),
        "+v"(xg[24]), "+v"(xg[25]), "+v"(xg[26]), "+v"(xg[27]),
        "+v"(xg[28]), "+v"(xg[29]), "+v"(xg[30]), "+v"(xg[31])
        :: "memory");

    // P1: lane-per-row argmax + logsumexp (bit-identical math to r0/r6)
    {
        float bmax[4]; int bidx[4]; float bsum[4];
#pragma unroll
        for (int c = 0; c < 4; ++c) { bmax[c] = -1e30f; bidx[c] = 0; bsum[c] = 0.f; }
#pragma unroll
        for (int t = 0; t < 24; ++t) {
            const int c = t / 6;                  // compile-time per unrolled t
            const f32x4 v = va[t];
            const int base = t * 4;
            // ascending scan, strict '>' keeps first occurrence
            if (v[0] > bmax[c]) { bmax[c] = v[0]; bidx[c] = base + 0; }
            if (v[1] > bmax[c]) { bmax[c] = v[1]; bidx[c] = base + 1; }
            if (v[2] > bmax[c]) { bmax[c] = v[2]; bidx[c] = base + 2; }
            if (v[3] > bmax[c]) { bmax[c] = v[3]; bidx[c] = base + 3; }
            bsum[c] += __expf(v[0]) + __expf(v[1]) + __expf(v[2]) + __expf(v[3]);
        }
        float m = bmax[0]; int idx = bidx[0];
#pragma unroll
        for (int c = 1; c < 4; ++c)           // strict '>': earlier block wins ties
            if (bmax[c] > m) { m = bmax[c]; idx = bidx[c]; }
        const float lse = __logf((bsum[0] + bsum[1]) + (bsum[2] + bsum[3]));
        lpS[s][u] = make_float2(lse, (float)idx);
    }
    // Same-wave producer/consumer through LDS; DS pipe in-order. Drain.
    asm volatile("s_waitcnt lgkmcnt(0)" ::: "memory");

    // P3: sign-encoded ce table -> GLOBAL (row-major; per instr lanes u are
    // consecutive dwords -> 2 x 128 B coalesced segments per wave-instr).
    {
        const float fl = (float)lab_u;
        float* ceRow = ceG + (size_t)sb * CEF;
#pragma unroll
        for (int r = 0; r < LROWS; ++r) {
            const float2 lp = lpS[s][r];      // wave-uniform per half: broadcast
            const float  ce = lp.x - xg[r];   // strictly > 0
            ceRow[r * MLAB + u] = (lp.y == fl) ? ce : -ce;
        }
    }
}

// ---------------- K2: DP wavefront phase (compute-only) --------------------
__global__ __launch_bounds__(256, 4) void editloss_k2(
    const float* __restrict__ ceG,
    float* __restrict__ partial_sum, float* __restrict__ partial_cnt)
{
    __shared__ float  ceTab[SPB][CEF];   // 32 KB, same layout as fused kernel
    __shared__ float  psum[SPB];
    __shared__ float  pcnt[SPB];

    const int w    = threadIdx.x >> 6;
    const int lane = threadIdx.x & 63;
    const int g    = lane >> 5;
    const int u    = lane & 31;
    const int s    = w * SPW + g;

    // Stage this block's 8-sample ce slice: 2048 float4, coalesced, L3-hot.
    {
        const f32x4* src = (const f32x4*)(ceG + (size_t)blockIdx.x * (SPB * CEF));
        f32x4* dst = (f32x4*)&ceTab[0][0];
#pragma unroll
        for (int t = 0; t < 8; ++t)
            dst[t * 256 + threadIdx.x] = src[t * 256 + threadIdx.x];
    }
    __syncthreads();

    // Phase B: fused DP wavefront (r6 VERBATIM — DPP chain, same predication)
    // lane u = column j = u+1 (column 0 analytic). Carried: D|cnt<<8, ce-sum.
    const int j = u + 1;
    int   prevW = 0;   float prevCE = 0.f;
    int   diagW = 0;   float diagCE = 0.f;
#pragma unroll 4
    for (int d = 1; d <= LROWS + MLAB; ++d) {
        const int   lWs  = dpp_wshr1_i32(prevW);    // (i, j-1)
        const float lCEs = dpp_wshr1_f32(prevCE);
        const int i = d - j;
        // column 0 analytic: D(i,0)=i, cnt=0, ce=0
        const int   lW  = (u == 0) ? max(i, 0)     : lWs;
        const float lCE = (u == 0) ? 0.f           : lCEs;
        const int   dW  = (u == 0) ? max(i - 1, 0) : diagW;
        const float dCE = (u == 0) ? 0.f           : diagCE;
        int curW; float curCE;
        if (i <= 0) {                       // top row: D=j; i<0 lanes inactive
            curW = j; curCE = 0.f;
        } else if (i > LROWS) {             // column finished: hold final value
            curW = prevW; curCE = prevCE;
        } else {
            const int uD = prevW & 255, uC = prevW >> 8;
            const int lD = lW & 255,    lC = lW >> 8;
            const int dD = dW & 255,    dC = dW >> 8;
            const float ct  = ceTab[s][(i - 1) * MLAB + u];
            const int   c   = (ct < 0.f) ? 1 : 0;
            const int nD = min(min(uD, lD) + 1, dD + c);
            // reference backtrace tie-break: diag > up > left
            const bool dg = (dD + c == nD);
            const bool up = !dg && (uD + 1 == nD);
            int nC; float nCE;
            if (dg)      { nC = dC + 1; nCE = dCE + fabsf(ct); }
            else if (up) { nC = uC;     nCE = prevCE;          }
            else         { nC = lC;     nCE = lCE;             }
            curW = nD | (nC << 8);
            curCE = nCE;
        }
        diagW = lWs; diagCE = lCEs;         // raw shifted value becomes next diag
        prevW = curW; prevCE = curCE;
    }

    // lane u==31 (j=32) holds cell (32,32) after d=64
    if (u == 31) {
        const int cnt = prevW >> 8;
        psum[s] = (cnt > 0) ? prevCE / (float)cnt : 0.f;
        pcnt[s] = (cnt > 0) ? 1.f : 0.f;
    }
    __syncthreads();
    if (threadIdx.x == 0) {
        float ss = 0.f, cc = 0.f;
#pragma unroll
        for (int k = 0; k < SPB; ++k) { ss += psum[k]; cc += pcnt[k]; }
        partial_sum[blockIdx.x] = ss;
        partial_cnt[blockIdx.x] = cc;
    }
}

__global__ __launch_bounds__(256) void editloss_finalize(
    const float* __restrict__ partial_sum, const float* __restrict__ partial_cnt,
    float* __restrict__ out, int nblocks)
{
    float s = 0.f, c = 0.f;
    for (int k = threadIdx.x; k < nblocks; k += 256) {
        s += partial_sum[k];
        c += partial_cnt[k];
    }
#pragma unroll
    for (int d = 32; d >= 1; d >>= 1) {
        s += __shfl_xor(s, d);
        c += __shfl_xor(c, d);
    }
    __shared__ float ss[4], cc[4];
    const int w = threadIdx.x >> 6, lane = threadIdx.x & 63;
    if (lane == 0) { ss[w] = s; cc[w] = c; }
    __syncthreads();
    if (threadIdx.x == 0) {
        const float S  = ss[0] + ss[1] + ss[2] + ss[3];
        const float C2 = cc[0] + cc[1] + cc[2] + cc[3];
        out[0] = (C2 > 0.f) ? (S / C2) : 0.f;
    }
}

extern "C" void kernel_launch(void* const* d_in, const int* in_sizes, int n_in,
                              void* d_out, int out_size, void* d_ws, size_t ws_size,
                              hipStream_t stream) {
    const float* x = (const float*)d_in[0];
    const int*   y = (const int*)d_in[1];
    // d_in[2]=num_chars, d_in[3]=num_labels: constants L/M in this problem.
    float* out = (float*)d_out;

    float* ceG         = (float*)d_ws;               // BNUM*CEF floats (33.5 MB)
    float* partial_sum = ceG + (size_t)BNUM * CEF;   // NBLK floats
    float* partial_cnt = partial_sum + NBLK;         // NBLK floats

    editloss_k1<<<NBLK, 256, 0, stream>>>(x, y, ceG);
    editloss_k2<<<NBLK, 256, 0, stream>>>(ceG, partial_sum, partial_cnt);
    editloss_finalize<<<1, 256, 0, stream>>>(partial_sum, partial_cnt, out, NBLK);
}

// Round 8
// 178.336 us; speedup vs baseline: 1.0034x; 1.0034x over previous
//
#include <hip/hip_runtime.h>
#include <stdint.h>

// Problem constants (from reference setup_inputs)
#define BNUM  8192
#define LROWS 32
#define MLAB  32
#define CCLS  96
#define SPB   4                    // samples per block, 1 per wave for P1
#define NBLK  (BNUM/SPB)           // 2048 blocks of 256
#define XFL   (LROWS*CCLS)         // 3072 floats of x per sample
#define SFL   (XFL + 2*LROWS)      // +64 floats lse/pred -> 3136 floats/sample
// LDS per block: 4*3136*4 = 50176 B -> 3 blocks/CU = 12 waves/CU.

typedef float f32x4 __attribute__((ext_vector_type(4)));

// dpp wave_shr:1 — HW-verified bit-exact replacement for __shfl_up(...,1)
// (round 2, absmax 0.0); lanes 0/32 bound_ctrl zeros are overridden by the
// analytic column-0 injection in Phase B.
__device__ __forceinline__ int dpp_wshr1_i32(int v) {
    return __builtin_amdgcn_update_dpp(0, v, 0x138, 0xF, 0xF, true);
}
__device__ __forceinline__ float dpp_wshr1_f32(float v) {
    return __int_as_float(
        __builtin_amdgcn_update_dpp(0, __float_as_int(v), 0x138, 0xF, 0xF, true));
}

// Bank-swizzle of the 12 granules (16B) of a half-row, parameterized by row.
// Involution in k for fixed r (XOR within closed 8- and 4-blocks), so the
// same formula serves store-side inversion and load-side addressing.
__device__ __forceinline__ int swz12(int k, int r) {
    return (k < 8) ? (k ^ (r & 7)) : (8 + ((k - 8) ^ (r & 3)));
}

__device__ __forceinline__ void gload16(const float* g, float* l) {
    // wave-uniform LDS base; HW writes base + lane*16. Global addr is per-lane.
    __builtin_amdgcn_global_load_lds(
        (const __attribute__((address_space(1))) unsigned int*)g,
        (__attribute__((address_space(3))) unsigned int*)l,
        16, 0, 0);
}

__global__ __launch_bounds__(256, 3) void editloss_main(
    const float* __restrict__ x, const int* __restrict__ y,
    float* __restrict__ partial_sum, float* __restrict__ partial_cnt)
{
    __shared__ float S[SPB * SFL];       // 50176 B

    const int tid  = threadIdx.x;
    const int w    = tid >> 6;           // wave id = sample slot for P1
    const int lane = tid & 63;
    const int r    = lane & 31;          // row (P1) / DP column (Phase B)
    const int h    = lane >> 5;          // half-row select (P1) / sample half (B)

    const int    sb = blockIdx.x * SPB + w;
    const float* gx = x + (size_t)sb * XFL;
    float*       Sw = &S[w * SFL];

    // ---------- Stage own sample: sequential global stream -> LDS ----------
    // LDS is linear; the SOURCE address is pre-swizzled with the involution
    // so that LDS physical granule q holds logical granule inv(q). Per instr
    // the wave reads 1024 contiguous-modulo-128B bytes: 16 L1 sectors
    // (vs 64 for the old strided row loads).
#pragma unroll
    for (int t = 0; t < 12; ++t) {
        const int q   = t * 64 + lane;           // physical granule in sample
        const int rr  = (q * 683) >> 14;         // q/24 exact for q<768
        const int rem = q - rr * 24;
        const int hh  = (rem >= 12) ? 1 : 0;
        const int kp  = rem - 12 * hh;
        const int kk  = swz12(kp, rr);           // involution
        const int G   = rr * 24 + 12 * hh + kk;  // logical granule to fetch
        gload16(gx + G * 4, Sw + t * 256);
    }
    asm volatile("s_waitcnt vmcnt(0)" ::: "memory");

    // ---------- P1: half-row per lane, bit-exact 4-block scan ---------------
    // lane (r, h=0) owns cols 0..47 = reference blocks 0,1; (r, h=1) owns
    // cols 48..95 = blocks 2,3. Same element order, strict '>', same sumexp
    // association ((b0+b1)+(b2+b3)) as the verified kernel.
    {
        f32x4 va[12];
#pragma unroll
        for (int k = 0; k < 12; ++k) {
            const int p = r * 24 + h * 12 + swz12(k, r);
            va[k] = *(const f32x4*)(Sw + p * 4);
        }
        float bmA = -1e30f, bmB = -1e30f; int biA = 0, biB = 0;
        float bsA = 0.f, bsB = 0.f;
#pragma unroll
        for (int k = 0; k < 12; ++k) {
            const f32x4 v = va[k];
            const int base = h * 48 + k * 4;     // absolute column
            if (k < 6) {
                if (v[0] > bmA) { bmA = v[0]; biA = base + 0; }
                if (v[1] > bmA) { bmA = v[1]; biA = base + 1; }
                if (v[2] > bmA) { bmA = v[2]; biA = base + 2; }
                if (v[3] > bmA) { bmA = v[3]; biA = base + 3; }
                bsA += __expf(v[0]) + __expf(v[1]) + __expf(v[2]) + __expf(v[3]);
            } else {
                if (v[0] > bmB) { bmB = v[0]; biB = base + 0; }
                if (v[1] > bmB) { bmB = v[1]; biB = base + 1; }
                if (v[2] > bmB) { bmB = v[2]; biB = base + 2; }
                if (v[3] > bmB) { bmB = v[3]; biB = base + 3; }
                bsB += __expf(v[0]) + __expf(v[1]) + __expf(v[2]) + __expf(v[3]);
            }
        }
        // local combine (earlier block wins ties via strict '>')
        float mL = bmA; int iL = biA;
        if (bmB > mL) { mL = bmB; iL = biB; }
        const float sL = bsA + bsB;              // b0+b1 (h=0) or b2+b3 (h=1)
        // cross-half combine in reference order: blocks (0,1) then (2,3)
        const float mP = __shfl_xor(mL, 32);
        const int   iP = __shfl_xor(iL, 32);
        const float sP = __shfl_xor(sL, 32);
        const float mLo = h ? mP : mL;  const int iLo = h ? iP : iL;
        const float mHi = h ? mL : mP;  const int iHi = h ? iL : iP;
        const float sLo = h ? sP : sL;  const float sHi = h ? sL : sP;
        float m = mLo; int idx = iLo;
        if (mHi > m) { m = mHi; idx = iHi; }
        const float lse = __logf(sLo + sHi);
        if (h == 0) {
            Sw[XFL + r * 2 + 0] = lse;
            Sw[XFL + r * 2 + 1] = (float)idx;
        }
    }
    __syncthreads();          // all 4 samples staged + lse/pred published
    if (w >= 2) return;       // waves 2,3 done; 0,1 carry Phase B (2 samples ea)

    // ---------- ce build: signed table written over dead x rows -------------
    // B-wave w handles samples {2w (lanes<32), 2w+1 (lanes>=32)}. Lane u=r is
    // DP column r. ce[rr][u] overwrites physical granules 24rr..24rr+7 (x cols
    // 0..31 of row rr) AFTER that row's gather reads — same-wave DS is
    // in-order and later rows' data is untouched.
    const int    sLoc = w * 2 + h;
    const int    samp = blockIdx.x * SPB + sLoc;
    float*       Sg   = &S[sLoc * SFL];
    const int    lab  = y[samp * MLAB + r];
    {
        const int   hh = (lab >= 48) ? 1 : 0;
        const int   kq = (lab - 48 * hh) >> 2;
        const int   el = lab & 3;
        const float fl = (float)lab;
#pragma unroll
        for (int rr = 0; rr < LROWS; ++rr) {
            const float lse = Sg[XFL + rr * 2 + 0];
            const float prf = Sg[XFL + rr * 2 + 1];
            const int   p   = rr * 24 + 12 * hh + swz12(kq, rr);
            const float xg  = Sg[p * 4 + el];    // x[rr, lab]
            const float ce  = lse - xg;          // strictly > 0
            Sg[rr * 96 + r] = (prf == fl) ? ce : -ce;
        }
    }
    asm volatile("s_waitcnt lgkmcnt(0)" ::: "memory");

    // ---------- Phase B: DP wavefront (r6 verbatim, ct from LDS) ------------
    const int j = r + 1;
    int   prevW = 0;   float prevCE = 0.f;
    int   diagW = 0;   float diagCE = 0.f;
#pragma unroll 4
    for (int d = 1; d <= LROWS + MLAB; ++d) {
        const int   lWs  = dpp_wshr1_i32(prevW);    // (i, j-1)
        const float lCEs = dpp_wshr1_f32(prevCE);
        const int i = d - j;
        // column 0 analytic: D(i,0)=i, cnt=0, ce=0
        const int   lW  = (r == 0) ? max(i, 0)     : lWs;
        const float lCE = (r == 0) ? 0.f           : lCEs;
        const int   dW  = (r == 0) ? max(i - 1, 0) : diagW;
        const float dCE = (r == 0) ? 0.f           : diagCE;
        int curW; float curCE;
        if (i <= 0) {                       // top row: D=j; i<0 lanes inactive
            curW = j; curCE = 0.f;
        } else if (i > LROWS) {             // column finished: hold final value
            curW = prevW; curCE = prevCE;
        } else {
            const int uD = prevW & 255, uC = prevW >> 8;
            const int lD = lW & 255,    lC = lW >> 8;
            const int dD = dW & 255,    dC = dW >> 8;
            const float ct  = Sg[(i - 1) * 96 + r];
            const int   c   = (ct < 0.f) ? 1 : 0;
            const int nD = min(min(uD, lD) + 1, dD + c);
            // reference backtrace tie-break: diag > up > left
            const bool dg = (dD + c == nD);
            const bool up = !dg && (uD + 1 == nD);
            int nC; float nCE;
            if (dg)      { nC = dC + 1; nCE = dCE + fabsf(ct); }
            else if (up) { nC = uC;     nCE = prevCE;          }
            else         { nC = lC;     nCE = lCE;             }
            curW = nD | (nC << 8);
            curCE = nCE;
        }
        diagW = lWs; diagCE = lCEs;         // raw shifted value becomes next diag
        prevW = curW; prevCE = curCE;
    }

    // lanes r==31 of each half hold cell (32,32); write per-sample results.
    if (r == 31) {
        const int cnt = prevW >> 8;
        partial_sum[samp] = (cnt > 0) ? prevCE / (float)cnt : 0.f;
        partial_cnt[samp] = (cnt > 0) ? 1.f : 0.f;
    }
}

__global__ __launch_bounds__(256) void editloss_finalize(
    const float* __restrict__ partial_sum, const float* __restrict__ partial_cnt,
    float* __restrict__ out, int n)
{
    float s = 0.f, c = 0.f;
    for (int k = threadIdx.x; k < n; k += 256) {
        s += partial_sum[k];
        c += partial_cnt[k];
    }
#pragma unroll
    for (int d = 32; d >= 1; d >>= 1) {
        s += __shfl_xor(s, d);
        c += __shfl_xor(c, d);
    }
    __shared__ float ss[4], cc[4];
    const int w = threadIdx.x >> 6, lane = threadIdx.x & 63;
    if (lane == 0) { ss[w] = s; cc[w] = c; }
    __syncthreads();
    if (threadIdx.x == 0) {
        const float S  = ss[0] + ss[1] + ss[2] + ss[3];
        const float C2 = cc[0] + cc[1] + cc[2] + cc[3];
        out[0] = (C2 > 0.f) ? (S / C2) : 0.f;
    }
}

extern "C" void kernel_launch(void* const* d_in, const int* in_sizes, int n_in,
                              void* d_out, int out_size, void* d_ws, size_t ws_size,
                              hipStream_t stream) {
    const float* x = (const float*)d_in[0];
    const int*   y = (const int*)d_in[1];
    // d_in[2]=num_chars, d_in[3]=num_labels: constants L/M in this problem.
    float* out = (float*)d_out;

    float* partial_sum = (float*)d_ws;           // BNUM floats
    float* partial_cnt = partial_sum + BNUM;     // BNUM floats

    editloss_main<<<NBLK, 256, 0, stream>>>(x, y, partial_sum, partial_cnt);
    editloss_finalize<<<1, 256, 0, stream>>>(partial_sum, partial_cnt, out, BNUM);
}